// Round 2
// baseline (5888.607 us; speedup 1.0000x reference)
//
#include <hip/hip_runtime.h>
#include <stdint.h>

// Problem constants
#define NB    32      // batch
#define NS    64      // src seq
#define TDEC  63      // decode steps (T-1)
#define NE    512     // embed dim
#define NH    1024    // hidden
#define NV    32000   // vocab

typedef float  floatx4 __attribute__((ext_vector_type(4)));
typedef short  short8  __attribute__((ext_vector_type(8)));

__device__ __forceinline__ float bf2f(short s) {
  return __uint_as_float(((uint32_t)(uint16_t)s) << 16);
}
__device__ __forceinline__ short f2bf(float f) {
  uint32_t u = __float_as_uint(f);
  uint32_t r = (u + 0x7fffu + ((u >> 16) & 1u)) >> 16;  // RNE
  return (short)(uint16_t)r;
}
__device__ __forceinline__ float sigm(float x) { return 1.f / (1.f + expf(-x)); }

// ---------------------------------------------------------------------------
// Transpose + f32->bf16 convert: W[K][N] (f32) -> Wt[N][K] (bf16)
// ---------------------------------------------------------------------------
__global__ __launch_bounds__(256) void transpose_bf(
    const float* __restrict__ W, short* __restrict__ Wt, int K, int N)
{
  __shared__ float tile[32][33];
  int k0 = blockIdx.x * 32, n0 = blockIdx.y * 32;
  int tx = threadIdx.x & 31, ty = threadIdx.x >> 5;  // 32 x 8
#pragma unroll
  for (int r = 0; r < 32; r += 8)
    tile[ty + r][tx] = W[(size_t)(k0 + ty + r) * N + n0 + tx];
  __syncthreads();
#pragma unroll
  for (int r = 0; r < 32; r += 8)
    Wt[(size_t)(n0 + ty + r) * K + k0 + tx] = f2bf(tile[tx][ty + r]);
}

// Split transpose: W[K][N] f32 -> Wt_hi[N][K], Wt_lo[N][K] bf16 (hi + lo ~ f32)
__global__ __launch_bounds__(256) void transpose_bf_split(
    const float* __restrict__ W, short* __restrict__ Wt_hi,
    short* __restrict__ Wt_lo, int K, int N)
{
  __shared__ float tile[32][33];
  int k0 = blockIdx.x * 32, n0 = blockIdx.y * 32;
  int tx = threadIdx.x & 31, ty = threadIdx.x >> 5;
#pragma unroll
  for (int r = 0; r < 32; r += 8)
    tile[ty + r][tx] = W[(size_t)(k0 + ty + r) * N + n0 + tx];
  __syncthreads();
#pragma unroll
  for (int r = 0; r < 32; r += 8) {
    float v = tile[tx][ty + r];
    short h = f2bf(v);
    short l = f2bf(v - bf2f(h));
    size_t o = (size_t)(n0 + ty + r) * K + k0 + tx;
    Wt_hi[o] = h; Wt_lo[o] = l;
  }
}

// ---------------------------------------------------------------------------
// Gather embeddings -> xs_bf, transpose-init h_ring slot0 / c_buf ([k][b]).
// ---------------------------------------------------------------------------
__global__ __launch_bounds__(256) void gather_init(
    const int* __restrict__ target, const float* __restrict__ emb,
    const float* __restrict__ h0, const float* __restrict__ c0,
    short* __restrict__ xs, float* __restrict__ h_ring, float* __restrict__ c_buf)
{
  const int NXS = TDEC * NB * NE;            // 1032192
  const int NH32 = NH * NB;                  // 32768
  int total = NXS + 2 * NH32;
  for (int idx = blockIdx.x * 256 + threadIdx.x; idx < total; idx += gridDim.x * 256) {
    if (idx < NXS) {
      int row = idx >> 9, e = idx & 511;     // row = t*32+b
      int t = row >> 5, b = row & 31;
      int token = target[b * 64 + t];
      xs[idx] = f2bf(emb[(size_t)token * NE + e]);
    } else if (idx < NXS + NH32) {
      int r = idx - NXS; int k = r >> 5, b = r & 31;
      h_ring[r] = h0[b * NH + k];
    } else {
      int r = idx - NXS - NH32; int k = r >> 5, b = r & 31;
      c_buf[r] = c0[b * NH + k];
    }
  }
}

// ---------------------------------------------------------------------------
// bf16 MFMA GEMM: C[M][N] = A[M][K] * Bt[N][K]^T + bias
// A bf16; Bt pre-transposed bf16. OUT_BF: 1 -> bf16 out, 0 -> f32 out.
// BM=BN=128, BK=32, 256 thr, 4 waves (2x2).
// ---------------------------------------------------------------------------
template<int OUT_BF>
__global__ __launch_bounds__(256) void gemm_kernel(
    const short* __restrict__ Ab, const short* __restrict__ Bt,
    void* __restrict__ Cptr, const float* __restrict__ bias,
    int M, int N, int K)
{
  __shared__ short As[128 * 40];   // padded K-stride 40
  __shared__ short Bs[128 * 40];
  const int m0 = blockIdx.x * 128;
  const int n0 = blockIdx.y * 128;
  const int tid = threadIdx.x;
  const int lane = tid & 63;
  const int wid = tid >> 6;
  const int wr = wid >> 1, wc = wid & 1;

  floatx4 acc[4][4] = {};
  const int row = tid >> 1;          // 0..127
  const int kh  = (tid & 1) << 4;    // 0 or 16

  for (int k0 = 0; k0 < K; k0 += 32) {
    {
      int gm = m0 + row;
      short8 lo, hi;
      if (gm < M) {
        const short* src = Ab + (size_t)gm * K + k0 + kh;
        lo = *(const short8*)src;
        hi = *(const short8*)(src + 8);
      } else {
#pragma unroll
        for (int c = 0; c < 8; ++c) { lo[c] = 0; hi[c] = 0; }
      }
      *(short8*)&As[row * 40 + kh]     = lo;
      *(short8*)&As[row * 40 + kh + 8] = hi;
    }
    {
      const short* src = Bt + (size_t)(n0 + row) * K + k0 + kh;
      *(short8*)&Bs[row * 40 + kh]     = *(const short8*)src;
      *(short8*)&Bs[row * 40 + kh + 8] = *(const short8*)(src + 8);
    }
    __syncthreads();

    const int kA = (lane >> 4) << 3;   // 0,8,16,24
    const int rsel = lane & 15;
    short8 af[4], bfr[4];
#pragma unroll
    for (int mi = 0; mi < 4; ++mi)
      af[mi] = *(const short8*)&As[(wr * 64 + mi * 16 + rsel) * 40 + kA];
#pragma unroll
    for (int ni = 0; ni < 4; ++ni)
      bfr[ni] = *(const short8*)&Bs[(wc * 64 + ni * 16 + rsel) * 40 + kA];
#pragma unroll
    for (int mi = 0; mi < 4; ++mi)
#pragma unroll
      for (int ni = 0; ni < 4; ++ni)
        acc[mi][ni] = __builtin_amdgcn_mfma_f32_16x16x32_bf16(af[mi], bfr[ni], acc[mi][ni], 0, 0, 0);
    __syncthreads();
  }

  const int crow = (lane >> 4) * 4;
  const int ccol = lane & 15;
#pragma unroll
  for (int mi = 0; mi < 4; ++mi) {
#pragma unroll
    for (int ni = 0; ni < 4; ++ni) {
      int gn = n0 + wc * 64 + ni * 16 + ccol;
      float bv = bias[gn];
#pragma unroll
      for (int i = 0; i < 4; ++i) {
        int gm = m0 + wr * 64 + mi * 16 + crow + i;
        if (gm < M) {
          float v = acc[mi][ni][i] + bv;
          if (OUT_BF) ((short*)Cptr)[(size_t)gm * N + gn] = f2bf(v);
          else        ((float*)Cptr)[(size_t)gm * N + gn] = v;
        }
      }
    }
  }
}

// ---------------------------------------------------------------------------
// Split-precision MFMA GEMM (~fp32 accuracy): C = A[M][K](f32) * Bt^T + bias
// A split to hi/lo bf16 in staging; Bt_hi/Bt_lo pre-split. f32 out.
// acc += a_hi*b_hi + a_hi*b_lo + a_lo*b_hi  (rel err ~2^-17)
// ---------------------------------------------------------------------------
__global__ __launch_bounds__(256) void gemm_split(
    const float* __restrict__ A, const short* __restrict__ Bt_hi,
    const short* __restrict__ Bt_lo, float* __restrict__ C,
    const float* __restrict__ bias, int M, int N, int K)
{
  __shared__ short As_hi[128 * 40];
  __shared__ short As_lo[128 * 40];
  __shared__ short Bs_hi[128 * 40];
  __shared__ short Bs_lo[128 * 40];
  const int m0 = blockIdx.x * 128;
  const int n0 = blockIdx.y * 128;
  const int tid = threadIdx.x;
  const int lane = tid & 63;
  const int wid = tid >> 6;
  const int wr = wid >> 1, wc = wid & 1;

  floatx4 acc[4][4] = {};
  const int row = tid >> 1;
  const int kh  = (tid & 1) << 4;

  for (int k0 = 0; k0 < K; k0 += 32) {
    {
      const float* src = A + (size_t)(m0 + row) * K + k0 + kh;
      short8 h0v, h1, l0, l1;
#pragma unroll
      for (int c = 0; c < 8; ++c) {
        float v = src[c];
        short h = f2bf(v); h0v[c] = h; l0[c] = f2bf(v - bf2f(h));
        float w = src[c + 8];
        short g = f2bf(w); h1[c] = g; l1[c] = f2bf(w - bf2f(g));
      }
      *(short8*)&As_hi[row * 40 + kh]     = h0v;
      *(short8*)&As_hi[row * 40 + kh + 8] = h1;
      *(short8*)&As_lo[row * 40 + kh]     = l0;
      *(short8*)&As_lo[row * 40 + kh + 8] = l1;
    }
    {
      size_t o = (size_t)(n0 + row) * K + k0 + kh;
      *(short8*)&Bs_hi[row * 40 + kh]     = *(const short8*)(Bt_hi + o);
      *(short8*)&Bs_hi[row * 40 + kh + 8] = *(const short8*)(Bt_hi + o + 8);
      *(short8*)&Bs_lo[row * 40 + kh]     = *(const short8*)(Bt_lo + o);
      *(short8*)&Bs_lo[row * 40 + kh + 8] = *(const short8*)(Bt_lo + o + 8);
    }
    __syncthreads();

    const int kA = (lane >> 4) << 3;
    const int rsel = lane & 15;
    short8 ah[4], al[4], bh[4], bl[4];
#pragma unroll
    for (int mi = 0; mi < 4; ++mi) {
      int off = (wr * 64 + mi * 16 + rsel) * 40 + kA;
      ah[mi] = *(const short8*)&As_hi[off];
      al[mi] = *(const short8*)&As_lo[off];
    }
#pragma unroll
    for (int ni = 0; ni < 4; ++ni) {
      int off = (wc * 64 + ni * 16 + rsel) * 40 + kA;
      bh[ni] = *(const short8*)&Bs_hi[off];
      bl[ni] = *(const short8*)&Bs_lo[off];
    }
#pragma unroll
    for (int mi = 0; mi < 4; ++mi)
#pragma unroll
      for (int ni = 0; ni < 4; ++ni) {
        floatx4 a = acc[mi][ni];
        a = __builtin_amdgcn_mfma_f32_16x16x32_bf16(al[mi], bh[ni], a, 0, 0, 0);
        a = __builtin_amdgcn_mfma_f32_16x16x32_bf16(ah[mi], bl[ni], a, 0, 0, 0);
        a = __builtin_amdgcn_mfma_f32_16x16x32_bf16(ah[mi], bh[ni], a, 0, 0, 0);
        acc[mi][ni] = a;
      }
    __syncthreads();
  }

  const int crow = (lane >> 4) * 4;
  const int ccol = lane & 15;
#pragma unroll
  for (int mi = 0; mi < 4; ++mi) {
#pragma unroll
    for (int ni = 0; ni < 4; ++ni) {
      int gn = n0 + wc * 64 + ni * 16 + ccol;
      float bv = bias[gn];
#pragma unroll
      for (int i = 0; i < 4; ++i) {
        int gm = m0 + wr * 64 + mi * 16 + crow + i;
        C[(size_t)gm * N + gn] = acc[mi][ni][i] + bv;
      }
    }
  }
}

// ---------------------------------------------------------------------------
// One pipelined scan iteration i in [0,64]:
//   blocks [0,256)   : A(t=i)   gates = gates_x + h_{t-1}@W_hh ; LSTM -> h_t, c
//   blocks [256,288) : B(t=i-1) attention (fp32 enc_proj)
//   blocks [288,416) : C(t=i-2) out_t = tanh([h,ctx]@W_comb + b) -> bf16
// ---------------------------------------------------------------------------
__global__ __launch_bounds__(256) void scan_step(
    int iter,
    const float* __restrict__ Whh,    // (1024, 4096)
    const float* __restrict__ Wcomb,  // (2048, 1024)
    const float* __restrict__ bcomb,  // (1024)
    const float* __restrict__ encp,   // f32 (32*64, 1024)
    const short* __restrict__ gatesx, // bf16 (2016, 4096), rows t*32+b
    float* __restrict__ h_ring,       // 4 * 1024*32
    float* __restrict__ ctx_ring,     // 2 * 1024*32
    float* __restrict__ c_buf,        // 1024*32
    short* __restrict__ outs)         // bf16 (2016, 1024), rows b*63+t
{
  const int blk = blockIdx.x;
  const int tid = threadIdx.x;

  if (blk < 256) {
    // ---------------- Phase A: LSTM step t = iter ----------------
    const int t = iter;
    if (t > TDEC - 1) return;
    const float* hprev = h_ring + (size_t)(t & 3) * (NH * NB);
    float* hnew        = h_ring + (size_t)((t + 1) & 3) * (NH * NB);
    const int j0 = blk * 4;
    const int ks = tid >> 4;
    const int jj = (tid >> 2) & 3;
    const int bg = tid & 3;
    const int jg = j0 + jj;
    const int b0 = bg * 8;
    const int kbase = ks * 64;

    float acc0[8] = {}, acc1[8] = {}, acc2[8] = {}, acc3[8] = {};
    const float* wp = Whh + (size_t)kbase * 4096 + jg;
    const float* hp = hprev + kbase * 32 + b0;
    for (int kk = 0; kk < 64; ++kk) {
      float w0 = wp[0], w1 = wp[1024], w2 = wp[2048], w3 = wp[3072];
      float4 ha = *(const float4*)hp;
      float4 hb = *(const float4*)(hp + 4);
      float hv[8] = {ha.x, ha.y, ha.z, ha.w, hb.x, hb.y, hb.z, hb.w};
#pragma unroll
      for (int bb = 0; bb < 8; ++bb) {
        acc0[bb] = fmaf(w0, hv[bb], acc0[bb]);
        acc1[bb] = fmaf(w1, hv[bb], acc1[bb]);
        acc2[bb] = fmaf(w2, hv[bb], acc2[bb]);
        acc3[bb] = fmaf(w3, hv[bb], acc3[bb]);
      }
      wp += 4096; hp += 32;
    }
    __shared__ float red[16 * 4 * 4 * 33];
#pragma unroll
    for (int bb = 0; bb < 8; ++bb) {
      int base = ((ks * 4 + jj) * 4) * 33 + b0 + bb;
      red[base]      = acc0[bb];
      red[base + 33] = acc1[bb];
      red[base + 66] = acc2[bb];
      red[base + 99] = acc3[bb];
    }
    __syncthreads();
    if (tid < 128) {
      int jj2 = tid >> 5;
      int b   = tid & 31;
      int jg2 = j0 + jj2;
      float s0 = 0, s1 = 0, s2 = 0, s3 = 0;
#pragma unroll
      for (int kss = 0; kss < 16; ++kss) {
        int base = ((kss * 4 + jj2) * 4) * 33 + b;
        s0 += red[base]; s1 += red[base + 33]; s2 += red[base + 66]; s3 += red[base + 99];
      }
      const short* gx = gatesx + ((size_t)t * 32 + b) * 4096 + jg2;
      float gi = s0 + bf2f(gx[0]);
      float gf = s1 + bf2f(gx[1024]);
      float gg = s2 + bf2f(gx[2048]);
      float go = s3 + bf2f(gx[3072]);
      float co = c_buf[jg2 * 32 + b];
      float cn = sigm(gf) * co + sigm(gi) * tanhf(gg);
      float hn = sigm(go) * tanhf(cn);
      c_buf[jg2 * 32 + b] = cn;
      hnew[jg2 * 32 + b]  = hn;
    }
  } else if (blk < 288) {
    // ---------------- Phase B: attention for t = iter-1 (fp32) ----------------
    const int t = iter - 1;
    if (t < 0 || t > TDEC - 1) return;
    const int b = blk - 256;
    const float* h = h_ring + (size_t)((t + 1) & 3) * (NH * NB);
    float* ctx     = ctx_ring + (size_t)(t & 1) * (NH * NB);
    __shared__ float h_lds[NH];
    __shared__ float part[64 * 4];
    __shared__ float p_lds[64];
    for (int k = tid; k < NH; k += 256) h_lds[k] = h[k * 32 + b];
    __syncthreads();
    {
      int s  = tid & 63;
      int ks = tid >> 6;  // 0..3
      const float4* ep4 = (const float4*)(encp + ((size_t)(b * 64 + s)) * NH + ks * 256);
      const float4* hl4 = (const float4*)(h_lds + ks * 256);
      float a = 0;
#pragma unroll 8
      for (int k4 = 0; k4 < 64; ++k4) {
        float4 e = ep4[k4], hh = hl4[k4];
        a = fmaf(e.x, hh.x, a); a = fmaf(e.y, hh.y, a);
        a = fmaf(e.z, hh.z, a); a = fmaf(e.w, hh.w, a);
      }
      part[s * 4 + ks] = a;
    }
    __syncthreads();
    if (tid < 64) {
      float sc = part[tid * 4] + part[tid * 4 + 1] + part[tid * 4 + 2] + part[tid * 4 + 3];
      float m = sc;
#pragma unroll
      for (int off = 32; off; off >>= 1) m = fmaxf(m, __shfl_xor(m, off));
      float e = expf(sc - m);
      float sum = e;
#pragma unroll
      for (int off = 32; off; off >>= 1) sum += __shfl_xor(sum, off);
      p_lds[tid] = e / sum;
    }
    __syncthreads();
#pragma unroll
    for (int rep = 0; rep < 4; ++rep) {
      int j = tid + rep * 256;
      float a = 0;
      for (int ss = 0; ss < 64; ++ss)
        a = fmaf(p_lds[ss], encp[((size_t)(b * 64 + ss)) * NH + j], a);
      ctx[j * 32 + b] = a;
    }
  } else {
    // ---------------- Phase C: comb for t = iter-2 ----------------
    const int t = iter - 2;
    if (t < 0) return;
    const int local = blk - 288;
    const int j0 = local * 8;
    const float* h   = h_ring + (size_t)((t + 1) & 3) * (NH * NB);
    const float* ctx = ctx_ring + (size_t)(t & 1) * (NH * NB);
    const int ksC = tid >> 3;
    const int jjq = (tid >> 2) & 1;
    const int bgC = tid & 3;
    const int jb = j0 + jjq * 4;
    const int b0 = bgC * 8;
    const int kbase = ksC * 64;

    float acc[4][8] = {};
    const float* wp = Wcomb + (size_t)kbase * NH + jb;
    const float* sp = (ksC < 16) ? (h + kbase * 32 + b0)
                                 : (ctx + (kbase - 1024) * 32 + b0);
    for (int kk = 0; kk < 64; ++kk) {
      float4 wv = *(const float4*)wp;
      float4 ha = *(const float4*)sp;
      float4 hb = *(const float4*)(sp + 4);
      float wq[4] = {wv.x, wv.y, wv.z, wv.w};
      float hv[8] = {ha.x, ha.y, ha.z, ha.w, hb.x, hb.y, hb.z, hb.w};
#pragma unroll
      for (int q = 0; q < 4; ++q)
#pragma unroll
        for (int bb = 0; bb < 8; ++bb)
          acc[q][bb] = fmaf(wq[q], hv[bb], acc[q][bb]);
      wp += NH; sp += 32;
    }
    __shared__ float red2[32 * 8 * 33];
#pragma unroll
    for (int q = 0; q < 4; ++q)
#pragma unroll
      for (int bb = 0; bb < 8; ++bb)
        red2[(ksC * 8 + jjq * 4 + q) * 33 + b0 + bb] = acc[q][bb];
    __syncthreads();
    {
      int j = tid >> 5;
      int b = tid & 31;
      float s = 0;
#pragma unroll
      for (int kss = 0; kss < 32; ++kss) s += red2[(kss * 8 + j) * 33 + b];
      float v = tanhf(s + bcomb[j0 + j]);
      outs[((size_t)b * TDEC + t) * NH + j0 + j] = f2bf(v);
    }
  }
}

// ---------------------------------------------------------------------------
extern "C" void kernel_launch(void* const* d_in, const int* in_sizes, int n_in,
                              void* d_out, int out_size, void* d_ws, size_t ws_size,
                              hipStream_t stream)
{
  const int*   target = (const int*)  d_in[0];
  const float* src    = (const float*)d_in[1];
  const float* h0     = (const float*)d_in[2];
  const float* c0     = (const float*)d_in[3];
  const float* emb    = (const float*)d_in[4];
  const float* Wih    = (const float*)d_in[5];
  const float* Whh    = (const float*)d_in[6];
  const float* brnn   = (const float*)d_in[7];
  const float* Wattn  = (const float*)d_in[8];
  const float* battn  = (const float*)d_in[9];
  const float* Wcomb  = (const float*)d_in[10];
  const float* bcomb  = (const float*)d_in[11];
  const float* Wout   = (const float*)d_in[12];
  const float* bout   = (const float*)d_in[13];
  float* out = (float*)d_out;

  char* ws = (char*)d_ws;
  size_t off = 0;
  auto take = [&](size_t bytes) { char* p = ws + off; off += (bytes + 255) & ~(size_t)255; return p; };
  short* WoutT    = (short*)take((size_t)NV * NH * 2);          // 64 MB
  short* WattnTh  = (short*)take((size_t)NH * 2048 * 2);        // 4 MB
  short* WattnTl  = (short*)take((size_t)NH * 2048 * 2);        // 4 MB
  short* WihT     = (short*)take((size_t)4096 * NE * 2);        // 4 MB
  short* xs_bf    = (short*)take((size_t)TDEC * NB * NE * 2);   // 2 MB
  float* encp     = (float*)take((size_t)NB * NS * NH * 4);     // 8 MB (fp32)
  short* gatesx   = (short*)take((size_t)TDEC * NB * 4096 * 2); // 16.5 MB
  short* outs_bf  = (short*)take((size_t)TDEC * NB * NH * 2);   // 4 MB
  float* h_ring   = (float*)take((size_t)4 * NH * NB * 4);
  float* ctx_ring = (float*)take((size_t)2 * NH * NB * 4);
  float* c_buf    = (float*)take((size_t)NH * NB * 4);
  if (off > ws_size) return;

  // 1) weight transposes
  transpose_bf_split<<<dim3(2048 / 32, NH / 32), 256, 0, stream>>>(Wattn, WattnTh, WattnTl, 2048, NH);
  transpose_bf<<<dim3(NE / 32, 4096 / 32), 256, 0, stream>>>(Wih, WihT, NE, 4096);
  transpose_bf<<<dim3(NH / 32, NV / 32), 256, 0, stream>>>(Wout, WoutT, NH, NV);
  // 2) embedding gather + h0/c0 transpose-init
  gather_init<<<1024, 256, 0, stream>>>(target, emb, h0, c0, xs_bf, h_ring, c_buf);
  // 3) enc_proj = src_enc @ W_attn + b_attn  (fp32-accurate split GEMM)
  gemm_split<<<dim3(16, NH / 128), 256, 0, stream>>>(src, WattnTh, WattnTl, encp, battn, 2048, NH, 2048);
  // 4) gates_x = xs @ W_ih + b_rnn
  gemm_kernel<1><<<dim3(16, 4096 / 128), 256, 0, stream>>>(xs_bf, WihT, gatesx, brnn, TDEC * NB, 4096, NE);
  // 5) pipelined scan: 65 iterations
  for (int i = 0; i < TDEC + 2; ++i)
    scan_step<<<416, 256, 0, stream>>>(i, Whh, Wcomb, bcomb, encp, gatesx,
                                       h_ring, ctx_ring, c_buf, outs_bf);
  // 6) logits = outs @ W_out + b_out
  gemm_kernel<0><<<dim3(16, NV / 128), 256, 0, stream>>>(outs_bf, WoutT, out, bout, TDEC * NB, NV, NH);
}

// Round 4
// 4363.443 us; speedup vs baseline: 1.3495x; 1.3495x over previous
//
#include <hip/hip_runtime.h>
#include <stdint.h>

// Problem constants
#define NB    32      // batch
#define NS    64      // src seq
#define TDEC  63      // decode steps (T-1)
#define NE    512     // embed dim
#define NH    1024    // hidden
#define NV    32000   // vocab

typedef float  floatx4 __attribute__((ext_vector_type(4)));
typedef short  short8  __attribute__((ext_vector_type(8)));
typedef short  short4v __attribute__((ext_vector_type(4)));

__device__ __forceinline__ float bf2f(short s) {
  return __uint_as_float(((uint32_t)(uint16_t)s) << 16);
}
__device__ __forceinline__ short f2bf(float f) {
  uint32_t u = __float_as_uint(f);
  uint32_t r = (u + 0x7fffu + ((u >> 16) & 1u)) >> 16;  // RNE
  return (short)(uint16_t)r;
}
__device__ __forceinline__ float sigm(float x) { return 1.f / (1.f + expf(-x)); }

// ---------------------------------------------------------------------------
// Transpose + f32->bf16: W[K][N] -> Wt[r(n)][K].  PERM=1: r = (n&1023)*4+(n>>10)
// ---------------------------------------------------------------------------
template<int PERM>
__global__ __launch_bounds__(256) void transpose_bf(
    const float* __restrict__ W, short* __restrict__ Wt, int K, int N)
{
  __shared__ float tile[32][33];
  int k0 = blockIdx.x * 32, n0 = blockIdx.y * 32;
  int tx = threadIdx.x & 31, ty = threadIdx.x >> 5;  // 32 x 8
#pragma unroll
  for (int r = 0; r < 32; r += 8)
    tile[ty + r][tx] = W[(size_t)(k0 + ty + r) * N + n0 + tx];
  __syncthreads();
#pragma unroll
  for (int r = 0; r < 32; r += 8) {
    int n = n0 + ty + r;
    int rr = PERM ? ((n & 1023) * 4 + (n >> 10)) : n;
    Wt[(size_t)rr * K + k0 + tx] = f2bf(tile[tx][ty + r]);
  }
}

// Split transpose: W[K][N] f32 -> Wt_hi[r(n)][K], Wt_lo[r(n)][K] (hi+lo ~ f32)
template<int PERM>
__global__ __launch_bounds__(256) void transpose_bf_split(
    const float* __restrict__ W, short* __restrict__ Wt_hi,
    short* __restrict__ Wt_lo, int K, int N)
{
  __shared__ float tile[32][33];
  int k0 = blockIdx.x * 32, n0 = blockIdx.y * 32;
  int tx = threadIdx.x & 31, ty = threadIdx.x >> 5;
#pragma unroll
  for (int r = 0; r < 32; r += 8)
    tile[ty + r][tx] = W[(size_t)(k0 + ty + r) * N + n0 + tx];
  __syncthreads();
#pragma unroll
  for (int r = 0; r < 32; r += 8) {
    float v = tile[tx][ty + r];
    short h = f2bf(v);
    short l = f2bf(v - bf2f(h));
    int n = n0 + ty + r;
    int rr = PERM ? ((n & 1023) * 4 + (n >> 10)) : n;
    size_t o = (size_t)rr * K + k0 + tx;
    Wt_hi[o] = h; Wt_lo[o] = l;
  }
}

// ---------------------------------------------------------------------------
// Gather embeddings -> xs_bf; h0 -> hf/hhi/hlo slot0 [b][k]; c0 -> c_buf;
// brnn -> permuted brnn_p[c]=brnn[(c&3)*1024 + (c>>2)].
// ---------------------------------------------------------------------------
__global__ __launch_bounds__(256) void gather_init(
    const int* __restrict__ target, const float* __restrict__ emb,
    const float* __restrict__ h0, const float* __restrict__ c0,
    const float* __restrict__ brnn,
    short* __restrict__ xs, float* __restrict__ hf_ring,
    short* __restrict__ hhi_ring, short* __restrict__ hlo_ring,
    float* __restrict__ c_buf, float* __restrict__ brnn_p)
{
  const int NXS = TDEC * NB * NE;            // 1032192
  const int HN = NH * NB;                    // 32768
  int total = NXS + 2 * HN + 4096;
  for (int idx = blockIdx.x * 256 + threadIdx.x; idx < total; idx += gridDim.x * 256) {
    if (idx < NXS) {
      int row = idx >> 9, e = idx & 511;     // row = t*32+b
      int t = row >> 5, b = row & 31;
      int token = target[b * 64 + t];
      xs[idx] = f2bf(emb[(size_t)token * NE + e]);
    } else if (idx < NXS + HN) {
      int r = idx - NXS;
      float v = h0[r];                       // [b][k]
      hf_ring[r] = v;
      short hh = f2bf(v);
      hhi_ring[r] = hh;
      hlo_ring[r] = f2bf(v - bf2f(hh));
    } else if (idx < NXS + 2 * HN) {
      int r = idx - NXS - HN;
      c_buf[r] = c0[r];
    } else {
      int c = idx - NXS - 2 * HN;
      brnn_p[c] = brnn[(c & 3) * 1024 + (c >> 2)];
    }
  }
}

// ---------------------------------------------------------------------------
// bf16 MFMA GEMM: C[M][N] = A[M][K] * Bt[N][K]^T + bias
// ---------------------------------------------------------------------------
template<int OUT_BF>
__global__ __launch_bounds__(256) void gemm_kernel(
    const short* __restrict__ Ab, const short* __restrict__ Bt,
    void* __restrict__ Cptr, const float* __restrict__ bias,
    int M, int N, int K)
{
  __shared__ short As[128 * 40];   // padded K-stride 40
  __shared__ short Bs[128 * 40];
  const int m0 = blockIdx.x * 128;
  const int n0 = blockIdx.y * 128;
  const int tid = threadIdx.x;
  const int lane = tid & 63;
  const int wid = tid >> 6;
  const int wr = wid >> 1, wc = wid & 1;

  floatx4 acc[4][4] = {};
  const int row = tid >> 1;          // 0..127
  const int kh  = (tid & 1) << 4;    // 0 or 16

  for (int k0 = 0; k0 < K; k0 += 32) {
    {
      int gm = m0 + row;
      short8 lo, hi;
      if (gm < M) {
        const short* src = Ab + (size_t)gm * K + k0 + kh;
        lo = *(const short8*)src;
        hi = *(const short8*)(src + 8);
      } else {
#pragma unroll
        for (int c = 0; c < 8; ++c) { lo[c] = 0; hi[c] = 0; }
      }
      *(short8*)&As[row * 40 + kh]     = lo;
      *(short8*)&As[row * 40 + kh + 8] = hi;
    }
    {
      const short* src = Bt + (size_t)(n0 + row) * K + k0 + kh;
      *(short8*)&Bs[row * 40 + kh]     = *(const short8*)src;
      *(short8*)&Bs[row * 40 + kh + 8] = *(const short8*)(src + 8);
    }
    __syncthreads();

    const int kA = (lane >> 4) << 3;   // 0,8,16,24
    const int rsel = lane & 15;
    short8 af[4], bfr[4];
#pragma unroll
    for (int mi = 0; mi < 4; ++mi)
      af[mi] = *(const short8*)&As[(wr * 64 + mi * 16 + rsel) * 40 + kA];
#pragma unroll
    for (int ni = 0; ni < 4; ++ni)
      bfr[ni] = *(const short8*)&Bs[(wc * 64 + ni * 16 + rsel) * 40 + kA];
#pragma unroll
    for (int mi = 0; mi < 4; ++mi)
#pragma unroll
      for (int ni = 0; ni < 4; ++ni)
        acc[mi][ni] = __builtin_amdgcn_mfma_f32_16x16x32_bf16(af[mi], bfr[ni], acc[mi][ni], 0, 0, 0);
    __syncthreads();
  }

  const int crow = (lane >> 4) * 4;
  const int ccol = lane & 15;
#pragma unroll
  for (int mi = 0; mi < 4; ++mi) {
#pragma unroll
    for (int ni = 0; ni < 4; ++ni) {
      int gn = n0 + wc * 64 + ni * 16 + ccol;
      float bv = bias[gn];
#pragma unroll
      for (int i = 0; i < 4; ++i) {
        int gm = m0 + wr * 64 + mi * 16 + crow + i;
        if (gm < M) {
          float v = acc[mi][ni][i] + bv;
          if (OUT_BF) ((short*)Cptr)[(size_t)gm * N + gn] = f2bf(v);
          else        ((float*)Cptr)[(size_t)gm * N + gn] = v;
        }
      }
    }
  }
}

// ---------------------------------------------------------------------------
// Split-precision MFMA GEMM (~fp32): C = A(f32) * Bt^T + bias, f32 out.
// ---------------------------------------------------------------------------
__global__ __launch_bounds__(256) void gemm_split(
    const float* __restrict__ A, const short* __restrict__ Bt_hi,
    const short* __restrict__ Bt_lo, float* __restrict__ C,
    const float* __restrict__ bias, int M, int N, int K)
{
  __shared__ short As_hi[128 * 40];
  __shared__ short As_lo[128 * 40];
  __shared__ short Bs_hi[128 * 40];
  __shared__ short Bs_lo[128 * 40];
  const int m0 = blockIdx.x * 128;
  const int n0 = blockIdx.y * 128;
  const int tid = threadIdx.x;
  const int lane = tid & 63;
  const int wid = tid >> 6;
  const int wr = wid >> 1, wc = wid & 1;

  floatx4 acc[4][4] = {};
  const int row = tid >> 1;
  const int kh  = (tid & 1) << 4;

  for (int k0 = 0; k0 < K; k0 += 32) {
    {
      const float* src = A + (size_t)(m0 + row) * K + k0 + kh;
      short8 h0v, h1, l0, l1;
#pragma unroll
      for (int c = 0; c < 8; ++c) {
        float v = src[c];
        short h = f2bf(v); h0v[c] = h; l0[c] = f2bf(v - bf2f(h));
        float w = src[c + 8];
        short g = f2bf(w); h1[c] = g; l1[c] = f2bf(w - bf2f(g));
      }
      *(short8*)&As_hi[row * 40 + kh]     = h0v;
      *(short8*)&As_hi[row * 40 + kh + 8] = h1;
      *(short8*)&As_lo[row * 40 + kh]     = l0;
      *(short8*)&As_lo[row * 40 + kh + 8] = l1;
    }
    {
      size_t o = (size_t)(n0 + row) * K + k0 + kh;
      *(short8*)&Bs_hi[row * 40 + kh]     = *(const short8*)(Bt_hi + o);
      *(short8*)&Bs_hi[row * 40 + kh + 8] = *(const short8*)(Bt_hi + o + 8);
      *(short8*)&Bs_lo[row * 40 + kh]     = *(const short8*)(Bt_lo + o);
      *(short8*)&Bs_lo[row * 40 + kh + 8] = *(const short8*)(Bt_lo + o + 8);
    }
    __syncthreads();

    const int kA = (lane >> 4) << 3;
    const int rsel = lane & 15;
    short8 ah[4], al[4], bh[4], bl[4];
#pragma unroll
    for (int mi = 0; mi < 4; ++mi) {
      int off = (wr * 64 + mi * 16 + rsel) * 40 + kA;
      ah[mi] = *(const short8*)&As_hi[off];
      al[mi] = *(const short8*)&As_lo[off];
    }
#pragma unroll
    for (int ni = 0; ni < 4; ++ni) {
      int off = (wc * 64 + ni * 16 + rsel) * 40 + kA;
      bh[ni] = *(const short8*)&Bs_hi[off];
      bl[ni] = *(const short8*)&Bs_lo[off];
    }
#pragma unroll
    for (int mi = 0; mi < 4; ++mi)
#pragma unroll
      for (int ni = 0; ni < 4; ++ni) {
        floatx4 a = acc[mi][ni];
        a = __builtin_amdgcn_mfma_f32_16x16x32_bf16(al[mi], bh[ni], a, 0, 0, 0);
        a = __builtin_amdgcn_mfma_f32_16x16x32_bf16(ah[mi], bl[ni], a, 0, 0, 0);
        a = __builtin_amdgcn_mfma_f32_16x16x32_bf16(ah[mi], bh[ni], a, 0, 0, 0);
        acc[mi][ni] = a;
      }
    __syncthreads();
  }

  const int crow = (lane >> 4) * 4;
  const int ccol = lane & 15;
#pragma unroll
  for (int mi = 0; mi < 4; ++mi) {
#pragma unroll
    for (int ni = 0; ni < 4; ++ni) {
      int gn = n0 + wc * 64 + ni * 16 + ccol;
      float bv = bias[gn];
#pragma unroll
      for (int i = 0; i < 4; ++i) {
        int gm = m0 + wr * 64 + mi * 16 + crow + i;
        C[(size_t)gm * N + gn] = acc[mi][ni][i] + bv;
      }
    }
  }
}

// ---------------------------------------------------------------------------
// Pipelined scan iteration i in [0,64], 80 blocks:
//   blk [0,32)  A(t=i):   gates = gatesx + h@Whh (split-MFMA, ~fp32), LSTM
//   blk [32,64) B(t=i-1): attention fp32 -> ctx (hi/lo bf16)
//   blk [64,80) C(t=i-2): out = tanh([h|ctx]@Wcomb + b) (split-MFMA) -> bf16
// h layout [b][k]. Rings: h mod-4 (slot(t)=(t+1)&3), ctx mod-2 (slot t&1).
// ---------------------------------------------------------------------------
__global__ __launch_bounds__(256) void scan_step(
    int iter,
    const short* __restrict__ Whp_hi,  // bf16 [4096 c][1024], c = 4j+gate
    const short* __restrict__ Whp_lo,
    const short* __restrict__ WcT_hi,  // bf16 [1024 j][2048]
    const short* __restrict__ WcT_lo,
    const float* __restrict__ bcomb,   // (1024)
    const float* __restrict__ encp,    // f32 [2048 rows b*64+s][1024]
    const short* __restrict__ gatesx,  // bf16 [2016 rows t*32+b][4096 c-perm]
    short* __restrict__ hhi_ring,      // 4 * 32*1024 bf16 [b][k]
    short* __restrict__ hlo_ring,
    float* __restrict__ hf_ring,       // 4 * 32*1024 f32  [b][k]
    short* __restrict__ ctxhi_ring,    // 2 * 32*1024 bf16 [b][k]
    short* __restrict__ ctxlo_ring,
    float* __restrict__ c_buf,         // 32*1024 f32 [b][k]
    short* __restrict__ outs)          // bf16 [2016 rows b*63+t][1024]
{
  __shared__ float smem[32 * 132];
  const int blk = blockIdx.x;
  const int tid = threadIdx.x;
  const int lane = tid & 63;
  const int wid = tid >> 6;
  const int rsel = lane & 15;
  const int kA = (lane >> 4) * 8;
  const int crow = (lane >> 4) * 4;
  const int ccol = lane & 15;

  if (blk < 32) {
    // ---------------- Phase A: LSTM step t = iter ----------------
    const int t = iter;
    if (t >= TDEC) return;
    const size_t spv = (size_t)(t & 3) * (NH * NB);
    const size_t snw = (size_t)((t + 1) & 3) * (NH * NB);
    const short* Hh = hhi_ring + spv;
    const short* Hl = hlo_ring + spv;
    const int c0 = blk * 128;
    const int cw = c0 + wid * 32;

    floatx4 acc[2][2] = {};
    const short* wh0 = Whp_hi + (size_t)(cw + rsel) * NH + kA;
    const short* wl0 = Whp_lo + (size_t)(cw + rsel) * NH + kA;
    const short* wh1 = Whp_hi + (size_t)(cw + 16 + rsel) * NH + kA;
    const short* wl1 = Whp_lo + (size_t)(cw + 16 + rsel) * NH + kA;
    const size_t r0 = (size_t)rsel * NH + kA;
    const size_t r1 = (size_t)(16 + rsel) * NH + kA;
    for (int k0 = 0; k0 < NH; k0 += 32) {
      short8 a0h = *(const short8*)(Hh + r0 + k0);
      short8 a0l = *(const short8*)(Hl + r0 + k0);
      short8 a1h = *(const short8*)(Hh + r1 + k0);
      short8 a1l = *(const short8*)(Hl + r1 + k0);
      short8 b0h = *(const short8*)(wh0 + k0);
      short8 b0l = *(const short8*)(wl0 + k0);
      short8 b1h = *(const short8*)(wh1 + k0);
      short8 b1l = *(const short8*)(wl1 + k0);
      acc[0][0] = __builtin_amdgcn_mfma_f32_16x16x32_bf16(a0l, b0h, acc[0][0], 0, 0, 0);
      acc[0][0] = __builtin_amdgcn_mfma_f32_16x16x32_bf16(a0h, b0l, acc[0][0], 0, 0, 0);
      acc[0][0] = __builtin_amdgcn_mfma_f32_16x16x32_bf16(a0h, b0h, acc[0][0], 0, 0, 0);
      acc[0][1] = __builtin_amdgcn_mfma_f32_16x16x32_bf16(a0l, b1h, acc[0][1], 0, 0, 0);
      acc[0][1] = __builtin_amdgcn_mfma_f32_16x16x32_bf16(a0h, b1l, acc[0][1], 0, 0, 0);
      acc[0][1] = __builtin_amdgcn_mfma_f32_16x16x32_bf16(a0h, b1h, acc[0][1], 0, 0, 0);
      acc[1][0] = __builtin_amdgcn_mfma_f32_16x16x32_bf16(a1l, b0h, acc[1][0], 0, 0, 0);
      acc[1][0] = __builtin_amdgcn_mfma_f32_16x16x32_bf16(a1h, b0l, acc[1][0], 0, 0, 0);
      acc[1][0] = __builtin_amdgcn_mfma_f32_16x16x32_bf16(a1h, b0h, acc[1][0], 0, 0, 0);
      acc[1][1] = __builtin_amdgcn_mfma_f32_16x16x32_bf16(a1l, b1h, acc[1][1], 0, 0, 0);
      acc[1][1] = __builtin_amdgcn_mfma_f32_16x16x32_bf16(a1h, b1l, acc[1][1], 0, 0, 0);
      acc[1][1] = __builtin_amdgcn_mfma_f32_16x16x32_bf16(a1h, b1h, acc[1][1], 0, 0, 0);
    }
    // dump gates to LDS [32 b][128 c] stride 132
#pragma unroll
    for (int mi = 0; mi < 2; ++mi)
#pragma unroll
      for (int ni = 0; ni < 2; ++ni) {
        int c = wid * 32 + ni * 16 + ccol;
#pragma unroll
        for (int i = 0; i < 4; ++i)
          smem[(mi * 16 + crow + i) * 132 + c] = acc[mi][ni][i];
      }
    __syncthreads();
    // pointwise LSTM
    const int b = tid & 31;
    float* hnew_f = hf_ring + snw;
    short* hnew_h = hhi_ring + snw;
    short* hnew_l = hlo_ring + snw;
#pragma unroll
    for (int r = 0; r < 4; ++r) {
      int jl = (tid >> 5) + r * 8;          // 0..31
      int jg = (c0 >> 2) + jl;              // global j
      const float* g4 = &smem[b * 132 + jl * 4];
      const short* gx = gatesx + ((size_t)t * 32 + b) * 4096 + c0 + jl * 4;
      short4v gxv = *(const short4v*)gx;
      float gi = g4[0] + bf2f(gxv[0]);
      float gf = g4[1] + bf2f(gxv[1]);
      float gg = g4[2] + bf2f(gxv[2]);
      float go = g4[3] + bf2f(gxv[3]);
      float co = c_buf[b * NH + jg];
      float cn = sigm(gf) * co + sigm(gi) * tanhf(gg);
      float hn = sigm(go) * tanhf(cn);
      c_buf[b * NH + jg] = cn;
      hnew_f[b * NH + jg] = hn;
      short hh = f2bf(hn);
      hnew_h[b * NH + jg] = hh;
      hnew_l[b * NH + jg] = f2bf(hn - bf2f(hh));
    }
  } else if (blk < 64) {
    // ---------------- Phase B: attention t = iter-1 (fp32) ----------------
    const int t = iter - 1;
    if (t < 0 || t >= TDEC) return;
    const int b = blk - 32;
    const float* h = hf_ring + (size_t)((t + 1) & 3) * (NH * NB) + b * NH;
    const size_t cslot = (size_t)(t & 1) * (NH * NB) + b * NH;
    short* ctxh = ctxhi_ring + cslot;
    short* ctxl = ctxlo_ring + cslot;
    float* h_lds = smem;            // 1024
    float* sc_lds = smem + 1024;    // 64
    float* p_lds = smem + 1088;     // 64
    {
      float4 v = ((const float4*)h)[tid];
      ((float4*)h_lds)[tid] = v;
    }
    __syncthreads();
    {
      const float4* hl4 = (const float4*)(h_lds + lane * 16);
      float4 hv0 = hl4[0], hv1 = hl4[1], hv2 = hl4[2], hv3 = hl4[3];
      for (int si = 0; si < 16; ++si) {
        int s = wid * 16 + si;
        const float4* ep = (const float4*)(encp + ((size_t)(b * 64 + s)) * NH + lane * 16);
        float4 e0 = ep[0], e1 = ep[1], e2 = ep[2], e3 = ep[3];
        float a = e0.x * hv0.x + e0.y * hv0.y + e0.z * hv0.z + e0.w * hv0.w;
        a = fmaf(e1.x, hv1.x, a); a = fmaf(e1.y, hv1.y, a);
        a = fmaf(e1.z, hv1.z, a); a = fmaf(e1.w, hv1.w, a);
        a = fmaf(e2.x, hv2.x, a); a = fmaf(e2.y, hv2.y, a);
        a = fmaf(e2.z, hv2.z, a); a = fmaf(e2.w, hv2.w, a);
        a = fmaf(e3.x, hv3.x, a); a = fmaf(e3.y, hv3.y, a);
        a = fmaf(e3.z, hv3.z, a); a = fmaf(e3.w, hv3.w, a);
#pragma unroll
        for (int off = 32; off; off >>= 1) a += __shfl_xor(a, off);
        if (lane == 0) sc_lds[s] = a;
      }
    }
    __syncthreads();
    if (tid < 64) {
      float sc = sc_lds[tid];
      float m = sc;
#pragma unroll
      for (int off = 32; off; off >>= 1) m = fmaxf(m, __shfl_xor(m, off));
      float e = expf(sc - m);
      float sum = e;
#pragma unroll
      for (int off = 32; off; off >>= 1) sum += __shfl_xor(sum, off);
      p_lds[tid] = e / sum;
    }
    __syncthreads();
    {
      int k4 = tid * 4;
      float a0 = 0, a1 = 0, a2 = 0, a3 = 0;
      const float* ep = encp + (size_t)(b * 64) * NH + k4;
      for (int s = 0; s < 64; ++s) {
        float p = p_lds[s];
        float4 e = *(const float4*)(ep + (size_t)s * NH);
        a0 = fmaf(p, e.x, a0); a1 = fmaf(p, e.y, a1);
        a2 = fmaf(p, e.z, a2); a3 = fmaf(p, e.w, a3);
      }
      short4v c4h, c4l;
      float av[4] = {a0, a1, a2, a3};
#pragma unroll
      for (int q = 0; q < 4; ++q) {
        short hh = f2bf(av[q]);
        c4h[q] = hh;
        c4l[q] = f2bf(av[q] - bf2f(hh));
      }
      *(short4v*)(ctxh + k4) = c4h;
      *(short4v*)(ctxl + k4) = c4l;
    }
  } else {
    // ---------------- Phase C: comb t = iter-2 (split-MFMA) ----------------
    const int t = iter - 2;
    if (t < 0) return;
    const int j0 = (blk - 64) * 64;
    const size_t hslot = (size_t)((t + 1) & 3) * (NH * NB);
    const size_t cslot = (size_t)(t & 1) * (NH * NB);
    const short* Hh = hhi_ring + hslot;
    const short* Hl = hlo_ring + hslot;
    const short* Ch = ctxhi_ring + cslot;
    const short* Cl = ctxlo_ring + cslot;
    const int jw = j0 + wid * 16;

    floatx4 acc[2] = {};
    const short* bh_p = WcT_hi + (size_t)(jw + rsel) * 2048 + kA;
    const short* bl_p = WcT_lo + (size_t)(jw + rsel) * 2048 + kA;
    const size_t r0 = (size_t)rsel * NH + kA;
    const size_t r1 = (size_t)(16 + rsel) * NH + kA;
    for (int k0 = 0; k0 < 2048; k0 += 32) {
      const short* sh = (k0 < NH) ? (Hh + k0) : (Ch + k0 - NH);
      const short* sl = (k0 < NH) ? (Hl + k0) : (Cl + k0 - NH);
      short8 a0h = *(const short8*)(sh + r0);
      short8 a0l = *(const short8*)(sl + r0);
      short8 a1h = *(const short8*)(sh + r1);
      short8 a1l = *(const short8*)(sl + r1);
      short8 b_h = *(const short8*)(bh_p + k0);
      short8 b_l = *(const short8*)(bl_p + k0);
      acc[0] = __builtin_amdgcn_mfma_f32_16x16x32_bf16(a0l, b_h, acc[0], 0, 0, 0);
      acc[0] = __builtin_amdgcn_mfma_f32_16x16x32_bf16(a0h, b_l, acc[0], 0, 0, 0);
      acc[0] = __builtin_amdgcn_mfma_f32_16x16x32_bf16(a0h, b_h, acc[0], 0, 0, 0);
      acc[1] = __builtin_amdgcn_mfma_f32_16x16x32_bf16(a1l, b_h, acc[1], 0, 0, 0);
      acc[1] = __builtin_amdgcn_mfma_f32_16x16x32_bf16(a1h, b_l, acc[1], 0, 0, 0);
      acc[1] = __builtin_amdgcn_mfma_f32_16x16x32_bf16(a1h, b_h, acc[1], 0, 0, 0);
    }
#pragma unroll
    for (int mi = 0; mi < 2; ++mi) {
      int j = jw + ccol;
      float bv = bcomb[j];
#pragma unroll
      for (int i = 0; i < 4; ++i) {
        int b = mi * 16 + crow + i;
        float v = tanhf(acc[mi][i] + bv);
        outs[((size_t)b * TDEC + t) * NH + j] = f2bf(v);
      }
    }
  }
}

// ---------------------------------------------------------------------------
extern "C" void kernel_launch(void* const* d_in, const int* in_sizes, int n_in,
                              void* d_out, int out_size, void* d_ws, size_t ws_size,
                              hipStream_t stream)
{
  const int*   target = (const int*)  d_in[0];
  const float* src    = (const float*)d_in[1];
  const float* h0     = (const float*)d_in[2];
  const float* c0     = (const float*)d_in[3];
  const float* emb    = (const float*)d_in[4];
  const float* Wih    = (const float*)d_in[5];
  const float* Whh    = (const float*)d_in[6];
  const float* brnn   = (const float*)d_in[7];
  const float* Wattn  = (const float*)d_in[8];
  const float* battn  = (const float*)d_in[9];
  const float* Wcomb  = (const float*)d_in[10];
  const float* bcomb  = (const float*)d_in[11];
  const float* Wout   = (const float*)d_in[12];
  const float* bout   = (const float*)d_in[13];
  float* out = (float*)d_out;

  char* ws = (char*)d_ws;
  size_t off = 0;
  auto take = [&](size_t bytes) { char* p = ws + off; off += (bytes + 255) & ~(size_t)255; return p; };
  short* WoutT    = (short*)take((size_t)NV * NH * 2);          // 64 MB
  short* WattnTh  = (short*)take((size_t)NH * 2048 * 2);        // 4 MB
  short* WattnTl  = (short*)take((size_t)NH * 2048 * 2);        // 4 MB
  short* WihTp    = (short*)take((size_t)4096 * NE * 2);        // 4 MB (perm rows)
  short* WhpHi    = (short*)take((size_t)4096 * NH * 2);        // 8 MB (perm rows)
  short* WhpLo    = (short*)take((size_t)4096 * NH * 2);        // 8 MB
  short* WcTHi    = (short*)take((size_t)NH * 2048 * 2);        // 4 MB
  short* WcTLo    = (short*)take((size_t)NH * 2048 * 2);        // 4 MB
  short* xs_bf    = (short*)take((size_t)TDEC * NB * NE * 2);   // 2 MB
  float* encp     = (float*)take((size_t)NB * NS * NH * 4);     // 8 MB (fp32)
  short* gatesx   = (short*)take((size_t)TDEC * NB * 4096 * 2); // 16.5 MB (perm cols)
  short* outs_bf  = (short*)take((size_t)TDEC * NB * NH * 2);   // 4 MB
  short* hhi_ring = (short*)take((size_t)4 * NH * NB * 2);
  short* hlo_ring = (short*)take((size_t)4 * NH * NB * 2);
  float* hf_ring  = (float*)take((size_t)4 * NH * NB * 4);
  short* ctxhi_rg = (short*)take((size_t)2 * NH * NB * 2);
  short* ctxlo_rg = (short*)take((size_t)2 * NH * NB * 2);
  float* c_buf    = (float*)take((size_t)NH * NB * 4);
  float* brnn_p   = (float*)take((size_t)4096 * 4);
  if (off > ws_size) return;

  // 1) weight transposes
  transpose_bf_split<0><<<dim3(2048 / 32, NH / 32), 256, 0, stream>>>(Wattn, WattnTh, WattnTl, 2048, NH);
  transpose_bf<1><<<dim3(NE / 32, 4096 / 32), 256, 0, stream>>>(Wih, WihTp, NE, 4096);
  transpose_bf_split<1><<<dim3(NH / 32, 4096 / 32), 256, 0, stream>>>(Whh, WhpHi, WhpLo, NH, 4096);
  transpose_bf_split<0><<<dim3(2048 / 32, NH / 32), 256, 0, stream>>>(Wcomb, WcTHi, WcTLo, 2048, NH);
  transpose_bf<0><<<dim3(NH / 32, NV / 32), 256, 0, stream>>>(Wout, WoutT, NH, NV);
  // 2) gathers / inits
  gather_init<<<1024, 256, 0, stream>>>(target, emb, h0, c0, brnn,
                                        xs_bf, hf_ring, hhi_ring, hlo_ring, c_buf, brnn_p);
  // 3) enc_proj = src_enc @ W_attn + b_attn  (fp32-accurate split GEMM)
  gemm_split<<<dim3(16, NH / 128), 256, 0, stream>>>(src, WattnTh, WattnTl, encp, battn, 2048, NH, 2048);
  // 4) gates_x = xs @ W_ih + b_rnn  (permuted columns c = 4j+gate)
  gemm_kernel<1><<<dim3(16, 4096 / 128), 256, 0, stream>>>(xs_bf, WihTp, gatesx, brnn_p, TDEC * NB, 4096, NE);
  // 5) pipelined scan: 65 iterations, 80 blocks each
  for (int i = 0; i < TDEC + 2; ++i)
    scan_step<<<80, 256, 0, stream>>>(i, WhpHi, WhpLo, WcTHi, WcTLo, bcomb, encp, gatesx,
                                      hhi_ring, hlo_ring, hf_ring, ctxhi_rg, ctxlo_rg,
                                      c_buf, outs_bf);
  // 6) logits = outs @ W_out + b_out
  gemm_kernel<0><<<dim3(16, NV / 128), 256, 0, stream>>>(outs_bf, WoutT, out, bout, TDEC * NB, NV, NH);
}

// Round 5
// 1299.092 us; speedup vs baseline: 4.5329x; 3.3588x over previous
//
#include <hip/hip_runtime.h>
#include <stdint.h>

// Problem constants
#define NB    32      // batch
#define NS    64      // src seq
#define TDEC  63      // decode steps (T-1)
#define NE    512     // embed dim
#define NH    1024    // hidden
#define NV    32000   // vocab

typedef float  floatx4 __attribute__((ext_vector_type(4)));
typedef short  short8  __attribute__((ext_vector_type(8)));
typedef short  short4v __attribute__((ext_vector_type(4)));

__device__ __forceinline__ float bf2f(short s) {
  return __uint_as_float(((uint32_t)(uint16_t)s) << 16);
}
__device__ __forceinline__ short f2bf(float f) {
  uint32_t u = __float_as_uint(f);
  uint32_t r = (u + 0x7fffu + ((u >> 16) & 1u)) >> 16;  // RNE
  return (short)(uint16_t)r;
}
__device__ __forceinline__ float sigm(float x) { return 1.f / (1.f + expf(-x)); }

// ---------------------------------------------------------------------------
// Transpose + f32->bf16: W[K][N] -> Wt[r(n)][K].  PERM=1: r = (n&1023)*4+(n>>10)
// ---------------------------------------------------------------------------
template<int PERM>
__global__ __launch_bounds__(256) void transpose_bf(
    const float* __restrict__ W, short* __restrict__ Wt, int K, int N)
{
  __shared__ float tile[32][33];
  int k0 = blockIdx.x * 32, n0 = blockIdx.y * 32;
  int tx = threadIdx.x & 31, ty = threadIdx.x >> 5;  // 32 x 8
#pragma unroll
  for (int r = 0; r < 32; r += 8)
    tile[ty + r][tx] = W[(size_t)(k0 + ty + r) * N + n0 + tx];
  __syncthreads();
#pragma unroll
  for (int r = 0; r < 32; r += 8) {
    int n = n0 + ty + r;
    int rr = PERM ? ((n & 1023) * 4 + (n >> 10)) : n;
    Wt[(size_t)rr * K + k0 + tx] = f2bf(tile[tx][ty + r]);
  }
}

// Split transpose: W[K][N] f32 -> Wt_hi[r(n)][K], Wt_lo[r(n)][K] (hi+lo ~ f32)
template<int PERM>
__global__ __launch_bounds__(256) void transpose_bf_split(
    const float* __restrict__ W, short* __restrict__ Wt_hi,
    short* __restrict__ Wt_lo, int K, int N)
{
  __shared__ float tile[32][33];
  int k0 = blockIdx.x * 32, n0 = blockIdx.y * 32;
  int tx = threadIdx.x & 31, ty = threadIdx.x >> 5;
#pragma unroll
  for (int r = 0; r < 32; r += 8)
    tile[ty + r][tx] = W[(size_t)(k0 + ty + r) * N + n0 + tx];
  __syncthreads();
#pragma unroll
  for (int r = 0; r < 32; r += 8) {
    float v = tile[tx][ty + r];
    short h = f2bf(v);
    short l = f2bf(v - bf2f(h));
    int n = n0 + ty + r;
    int rr = PERM ? ((n & 1023) * 4 + (n >> 10)) : n;
    size_t o = (size_t)rr * K + k0 + tx;
    Wt_hi[o] = h; Wt_lo[o] = l;
  }
}

// ---------------------------------------------------------------------------
// Gather embeddings -> xs_bf; h0 -> hf/hhi/hlo slot0 [b][k]; c0 -> c_buf;
// brnn -> permuted brnn_p[c]=brnn[(c&3)*1024 + (c>>2)].
// ---------------------------------------------------------------------------
__global__ __launch_bounds__(256) void gather_init(
    const int* __restrict__ target, const float* __restrict__ emb,
    const float* __restrict__ h0, const float* __restrict__ c0,
    const float* __restrict__ brnn,
    short* __restrict__ xs, float* __restrict__ hf_ring,
    short* __restrict__ hhi_ring, short* __restrict__ hlo_ring,
    float* __restrict__ c_buf, float* __restrict__ brnn_p)
{
  const int NXS = TDEC * NB * NE;            // 1032192
  const int HN = NH * NB;                    // 32768
  int total = NXS + 2 * HN + 4096;
  for (int idx = blockIdx.x * 256 + threadIdx.x; idx < total; idx += gridDim.x * 256) {
    if (idx < NXS) {
      int row = idx >> 9, e = idx & 511;     // row = t*32+b
      int t = row >> 5, b = row & 31;
      int token = target[b * 64 + t];
      xs[idx] = f2bf(emb[(size_t)token * NE + e]);
    } else if (idx < NXS + HN) {
      int r = idx - NXS;
      float v = h0[r];                       // [b][k]
      hf_ring[r] = v;
      short hh = f2bf(v);
      hhi_ring[r] = hh;
      hlo_ring[r] = f2bf(v - bf2f(hh));
    } else if (idx < NXS + 2 * HN) {
      int r = idx - NXS - HN;
      c_buf[r] = c0[r];
    } else {
      int c = idx - NXS - 2 * HN;
      brnn_p[c] = brnn[(c & 3) * 1024 + (c >> 2)];
    }
  }
}

// ---------------------------------------------------------------------------
// bf16 MFMA GEMM: C[M][N] = A[M][K] * Bt[N][K]^T + bias
// OUT_BF=0 (f32 out): LDS-staged coalesced float4 stores.
// ---------------------------------------------------------------------------
template<int OUT_BF>
__global__ __launch_bounds__(256) void gemm_kernel(
    const short* __restrict__ Ab, const short* __restrict__ Bt,
    void* __restrict__ Cptr, const float* __restrict__ bias,
    int M, int N, int K)
{
  __shared__ short As[128 * 40];   // padded K-stride 40
  __shared__ short Bs[128 * 40];
  __shared__ float cst[OUT_BF ? 1 : 32 * 132];
  const int m0 = blockIdx.x * 128;
  const int n0 = blockIdx.y * 128;
  const int tid = threadIdx.x;
  const int lane = tid & 63;
  const int wid = tid >> 6;
  const int wr = wid >> 1, wc = wid & 1;

  floatx4 acc[4][4] = {};
  const int row = tid >> 1;          // 0..127
  const int kh  = (tid & 1) << 4;    // 0 or 16

  for (int k0 = 0; k0 < K; k0 += 32) {
    {
      int gm = m0 + row;
      short8 lo, hi;
      if (gm < M) {
        const short* src = Ab + (size_t)gm * K + k0 + kh;
        lo = *(const short8*)src;
        hi = *(const short8*)(src + 8);
      } else {
#pragma unroll
        for (int c = 0; c < 8; ++c) { lo[c] = 0; hi[c] = 0; }
      }
      *(short8*)&As[row * 40 + kh]     = lo;
      *(short8*)&As[row * 40 + kh + 8] = hi;
    }
    {
      const short* src = Bt + (size_t)(n0 + row) * K + k0 + kh;
      *(short8*)&Bs[row * 40 + kh]     = *(const short8*)src;
      *(short8*)&Bs[row * 40 + kh + 8] = *(const short8*)(src + 8);
    }
    __syncthreads();

    const int kA = (lane >> 4) << 3;   // 0,8,16,24
    const int rsel = lane & 15;
    short8 af[4], bfr[4];
#pragma unroll
    for (int mi = 0; mi < 4; ++mi)
      af[mi] = *(const short8*)&As[(wr * 64 + mi * 16 + rsel) * 40 + kA];
#pragma unroll
    for (int ni = 0; ni < 4; ++ni)
      bfr[ni] = *(const short8*)&Bs[(wc * 64 + ni * 16 + rsel) * 40 + kA];
#pragma unroll
    for (int mi = 0; mi < 4; ++mi)
#pragma unroll
      for (int ni = 0; ni < 4; ++ni)
        acc[mi][ni] = __builtin_amdgcn_mfma_f32_16x16x32_bf16(af[mi], bfr[ni], acc[mi][ni], 0, 0, 0);
    __syncthreads();
  }

  const int crow = (lane >> 4) * 4;
  const int ccol = lane & 15;
  if (OUT_BF) {
#pragma unroll
    for (int mi = 0; mi < 4; ++mi) {
#pragma unroll
      for (int ni = 0; ni < 4; ++ni) {
        int gn = n0 + wc * 64 + ni * 16 + ccol;
        float bv = bias[gn];
#pragma unroll
        for (int i = 0; i < 4; ++i) {
          int gm = m0 + wr * 64 + mi * 16 + crow + i;
          if (gm < M)
            ((short*)Cptr)[(size_t)gm * N + gn] = f2bf(acc[mi][ni][i] + bv);
        }
      }
    }
  } else {
    // 4 passes of 32 rows; stage in LDS, store coalesced float4
#pragma unroll
    for (int p = 0; p < 4; ++p) {
      __syncthreads();
      if (wr == (p >> 1)) {
        int mi0 = (p & 1) * 2;
#pragma unroll
        for (int mm = 0; mm < 2; ++mm) {
#pragma unroll
          for (int ni = 0; ni < 4; ++ni) {
            int c = wc * 64 + ni * 16 + ccol;
#pragma unroll
            for (int i = 0; i < 4; ++i)
              cst[(mm * 16 + crow + i) * 132 + c] = acc[mi0 + mm][ni][i];
          }
        }
      }
      __syncthreads();
#pragma unroll
      for (int rep = 0; rep < 4; ++rep) {
        int cell = tid + rep * 256;        // 0..1023
        int r = cell >> 5, q = cell & 31;  // row 0..31, quad 0..31
        int gm = m0 + p * 32 + r;
        int gn = n0 + q * 4;
        if (gm < M) {
          float4 bv = *(const float4*)&bias[gn];
          float4 v;
          v.x = cst[r * 132 + q * 4 + 0] + bv.x;
          v.y = cst[r * 132 + q * 4 + 1] + bv.y;
          v.z = cst[r * 132 + q * 4 + 2] + bv.z;
          v.w = cst[r * 132 + q * 4 + 3] + bv.w;
          *(float4*)&((float*)Cptr)[(size_t)gm * N + gn] = v;
        }
      }
    }
  }
}

// ---------------------------------------------------------------------------
// Split-precision MFMA GEMM (~fp32): C = A(f32) * Bt^T + bias, f32 out.
// ---------------------------------------------------------------------------
__global__ __launch_bounds__(256) void gemm_split(
    const float* __restrict__ A, const short* __restrict__ Bt_hi,
    const short* __restrict__ Bt_lo, float* __restrict__ C,
    const float* __restrict__ bias, int M, int N, int K)
{
  __shared__ short As_hi[128 * 40];
  __shared__ short As_lo[128 * 40];
  __shared__ short Bs_hi[128 * 40];
  __shared__ short Bs_lo[128 * 40];
  const int m0 = blockIdx.x * 128;
  const int n0 = blockIdx.y * 128;
  const int tid = threadIdx.x;
  const int lane = tid & 63;
  const int wid = tid >> 6;
  const int wr = wid >> 1, wc = wid & 1;

  floatx4 acc[4][4] = {};
  const int row = tid >> 1;
  const int kh  = (tid & 1) << 4;

  for (int k0 = 0; k0 < K; k0 += 32) {
    {
      const float* src = A + (size_t)(m0 + row) * K + k0 + kh;
      short8 h0v, h1, l0, l1;
#pragma unroll
      for (int c = 0; c < 8; ++c) {
        float v = src[c];
        short h = f2bf(v); h0v[c] = h; l0[c] = f2bf(v - bf2f(h));
        float w = src[c + 8];
        short g = f2bf(w); h1[c] = g; l1[c] = f2bf(w - bf2f(g));
      }
      *(short8*)&As_hi[row * 40 + kh]     = h0v;
      *(short8*)&As_hi[row * 40 + kh + 8] = h1;
      *(short8*)&As_lo[row * 40 + kh]     = l0;
      *(short8*)&As_lo[row * 40 + kh + 8] = l1;
    }
    {
      size_t o = (size_t)(n0 + row) * K + k0 + kh;
      *(short8*)&Bs_hi[row * 40 + kh]     = *(const short8*)(Bt_hi + o);
      *(short8*)&Bs_hi[row * 40 + kh + 8] = *(const short8*)(Bt_hi + o + 8);
      *(short8*)&Bs_lo[row * 40 + kh]     = *(const short8*)(Bt_lo + o);
      *(short8*)&Bs_lo[row * 40 + kh + 8] = *(const short8*)(Bt_lo + o + 8);
    }
    __syncthreads();

    const int kA = (lane >> 4) << 3;
    const int rsel = lane & 15;
    short8 ah[4], al[4], bh[4], bl[4];
#pragma unroll
    for (int mi = 0; mi < 4; ++mi) {
      int off = (wr * 64 + mi * 16 + rsel) * 40 + kA;
      ah[mi] = *(const short8*)&As_hi[off];
      al[mi] = *(const short8*)&As_lo[off];
    }
#pragma unroll
    for (int ni = 0; ni < 4; ++ni) {
      int off = (wc * 64 + ni * 16 + rsel) * 40 + kA;
      bh[ni] = *(const short8*)&Bs_hi[off];
      bl[ni] = *(const short8*)&Bs_lo[off];
    }
#pragma unroll
    for (int mi = 0; mi < 4; ++mi)
#pragma unroll
      for (int ni = 0; ni < 4; ++ni) {
        floatx4 a = acc[mi][ni];
        a = __builtin_amdgcn_mfma_f32_16x16x32_bf16(al[mi], bh[ni], a, 0, 0, 0);
        a = __builtin_amdgcn_mfma_f32_16x16x32_bf16(ah[mi], bl[ni], a, 0, 0, 0);
        a = __builtin_amdgcn_mfma_f32_16x16x32_bf16(ah[mi], bh[ni], a, 0, 0, 0);
        acc[mi][ni] = a;
      }
    __syncthreads();
  }

  const int crow = (lane >> 4) * 4;
  const int ccol = lane & 15;
#pragma unroll
  for (int mi = 0; mi < 4; ++mi) {
#pragma unroll
    for (int ni = 0; ni < 4; ++ni) {
      int gn = n0 + wc * 64 + ni * 16 + ccol;
      float bv = bias[gn];
#pragma unroll
      for (int i = 0; i < 4; ++i) {
        int gm = m0 + wr * 64 + mi * 16 + crow + i;
        C[(size_t)gm * N + gn] = acc[mi][ni][i] + bv;
      }
    }
  }
}

// ---------------------------------------------------------------------------
// Pipelined scan iteration i in [0,64], 224 blocks x 512 threads:
//   blk [0,128)   A(t=i):   block owns 32 perm gate-cols; 8 waves split K=1024
//                           (4 iters each); LDS-reduce; pointwise LSTM
//   blk [128,160) B(t=i-1): attention fp32 -> ctx (hi/lo bf16)
//   blk [160,224) C(t=i-2): block owns 16 j-cols; 8 waves split K=2048
//                           (8 iters each); LDS-reduce; tanh -> outs bf16
// h layout [b][k]. Rings: h mod-4 (slot(t)=(t+1)&3), ctx mod-2 (slot t&1).
// ---------------------------------------------------------------------------
__global__ __launch_bounds__(512) void scan_step(
    int iter,
    const short* __restrict__ Whp_hi,  // bf16 [4096 c][1024], c = 4j+gate
    const short* __restrict__ Whp_lo,
    const short* __restrict__ WcT_hi,  // bf16 [1024 j][2048]
    const short* __restrict__ WcT_lo,
    const float* __restrict__ bcomb,   // (1024)
    const float* __restrict__ encp,    // f32 [2048 rows b*64+s][1024]
    const short* __restrict__ gatesx,  // bf16 [2016 rows t*32+b][4096 c-perm]
    short* __restrict__ hhi_ring,      // 4 * 32*1024 bf16 [b][k]
    short* __restrict__ hlo_ring,
    float* __restrict__ hf_ring,       // 4 * 32*1024 f32  [b][k]
    short* __restrict__ ctxhi_ring,    // 2 * 32*1024 bf16 [b][k]
    short* __restrict__ ctxlo_ring,
    float* __restrict__ c_buf,         // 32*1024 f32 [b][k]
    short* __restrict__ outs)          // bf16 [2016 rows b*63+t][1024]
{
  __shared__ float smem[8 * 32 * 33];  // 33.8 KB, reused per phase
  const int blk = blockIdx.x;
  const int tid = threadIdx.x;
  const int lane = tid & 63;
  const int wid = tid >> 6;           // 0..7
  const int rsel = lane & 15;
  const int kA = (lane >> 4) * 8;
  const int crow = (lane >> 4) * 4;
  const int ccol = lane & 15;

  if (blk < 128) {
    // ---------------- Phase A: LSTM step t = iter ----------------
    const int t = iter;
    if (t >= TDEC) return;
    const size_t spv = (size_t)(t & 3) * (NH * NB);
    const size_t snw = (size_t)((t + 1) & 3) * (NH * NB);
    const short* Hh = hhi_ring + spv;
    const short* Hl = hlo_ring + spv;
    const int c0 = blk * 32;          // this block's 32 perm-cols
    const int kb = wid * 128;         // wave's K-slice

    floatx4 acc[2][2] = {};
    const short* wh0 = Whp_hi + (size_t)(c0 + rsel) * NH + kb + kA;
    const short* wl0 = Whp_lo + (size_t)(c0 + rsel) * NH + kb + kA;
    const short* wh1 = Whp_hi + (size_t)(c0 + 16 + rsel) * NH + kb + kA;
    const short* wl1 = Whp_lo + (size_t)(c0 + 16 + rsel) * NH + kb + kA;
    const short* ha0 = Hh + (size_t)rsel * NH + kb + kA;
    const short* la0 = Hl + (size_t)rsel * NH + kb + kA;
    const short* ha1 = Hh + (size_t)(16 + rsel) * NH + kb + kA;
    const short* la1 = Hl + (size_t)(16 + rsel) * NH + kb + kA;
#pragma unroll
    for (int kk = 0; kk < 4; ++kk) {
      int k0 = kk * 32;
      short8 a0h = *(const short8*)(ha0 + k0);
      short8 a0l = *(const short8*)(la0 + k0);
      short8 a1h = *(const short8*)(ha1 + k0);
      short8 a1l = *(const short8*)(la1 + k0);
      short8 b0h = *(const short8*)(wh0 + k0);
      short8 b0l = *(const short8*)(wl0 + k0);
      short8 b1h = *(const short8*)(wh1 + k0);
      short8 b1l = *(const short8*)(wl1 + k0);
      acc[0][0] = __builtin_amdgcn_mfma_f32_16x16x32_bf16(a0l, b0h, acc[0][0], 0, 0, 0);
      acc[0][0] = __builtin_amdgcn_mfma_f32_16x16x32_bf16(a0h, b0l, acc[0][0], 0, 0, 0);
      acc[0][0] = __builtin_amdgcn_mfma_f32_16x16x32_bf16(a0h, b0h, acc[0][0], 0, 0, 0);
      acc[0][1] = __builtin_amdgcn_mfma_f32_16x16x32_bf16(a0l, b1h, acc[0][1], 0, 0, 0);
      acc[0][1] = __builtin_amdgcn_mfma_f32_16x16x32_bf16(a0h, b1l, acc[0][1], 0, 0, 0);
      acc[0][1] = __builtin_amdgcn_mfma_f32_16x16x32_bf16(a0h, b1h, acc[0][1], 0, 0, 0);
      acc[1][0] = __builtin_amdgcn_mfma_f32_16x16x32_bf16(a1l, b0h, acc[1][0], 0, 0, 0);
      acc[1][0] = __builtin_amdgcn_mfma_f32_16x16x32_bf16(a1h, b0l, acc[1][0], 0, 0, 0);
      acc[1][0] = __builtin_amdgcn_mfma_f32_16x16x32_bf16(a1h, b0h, acc[1][0], 0, 0, 0);
      acc[1][1] = __builtin_amdgcn_mfma_f32_16x16x32_bf16(a1l, b1h, acc[1][1], 0, 0, 0);
      acc[1][1] = __builtin_amdgcn_mfma_f32_16x16x32_bf16(a1h, b1l, acc[1][1], 0, 0, 0);
      acc[1][1] = __builtin_amdgcn_mfma_f32_16x16x32_bf16(a1h, b1h, acc[1][1], 0, 0, 0);
    }
    // partials -> LDS [wave][32 b][33-pad cols]
#pragma unroll
    for (int mi = 0; mi < 2; ++mi)
#pragma unroll
      for (int ni = 0; ni < 2; ++ni)
#pragma unroll
        for (int i = 0; i < 4; ++i)
          smem[wid * 1056 + (mi * 16 + crow + i) * 33 + ni * 16 + ccol] = acc[mi][ni][i];
    __syncthreads();
    if (tid < 256) {
      int b = tid & 31, jl = tid >> 5;     // jl 0..7
      float g[4];
#pragma unroll
      for (int q = 0; q < 4; ++q) {
        float s = 0;
#pragma unroll
        for (int w = 0; w < 8; ++w) s += smem[w * 1056 + b * 33 + jl * 4 + q];
        g[q] = s;
      }
      int jg = (c0 >> 2) + jl;
      const short* gx = gatesx + ((size_t)t * 32 + b) * 4096 + c0 + jl * 4;
      short4v gxv = *(const short4v*)gx;
      float gi = g[0] + bf2f(gxv[0]);
      float gf = g[1] + bf2f(gxv[1]);
      float gg = g[2] + bf2f(gxv[2]);
      float go = g[3] + bf2f(gxv[3]);
      float co = c_buf[b * NH + jg];
      float cn = sigm(gf) * co + sigm(gi) * tanhf(gg);
      float hn = sigm(go) * tanhf(cn);
      c_buf[b * NH + jg] = cn;
      hf_ring[snw + b * NH + jg] = hn;
      short hh = f2bf(hn);
      hhi_ring[snw + b * NH + jg] = hh;
      hlo_ring[snw + b * NH + jg] = f2bf(hn - bf2f(hh));
    }
  } else if (blk < 160) {
    // ---------------- Phase B: attention t = iter-1 (fp32) ----------------
    const int t = iter - 1;
    if (t < 0 || t >= TDEC) return;
    const int b = blk - 128;
    const float* h = hf_ring + (size_t)((t + 1) & 3) * (NH * NB) + b * NH;
    const size_t cslot = (size_t)(t & 1) * (NH * NB) + b * NH;
    short* ctxh = ctxhi_ring + cslot;
    short* ctxl = ctxlo_ring + cslot;
    float* h_lds = smem;            // 1024
    float* sc_lds = smem + 1024;    // 64
    float* p_lds = smem + 1088;     // 64
    if (tid < 256) {
      float4 v = ((const float4*)h)[tid];
      ((float4*)h_lds)[tid] = v;
    }
    __syncthreads();
    {
      const float4* hl4 = (const float4*)(h_lds + lane * 16);
      float4 hv0 = hl4[0], hv1 = hl4[1], hv2 = hl4[2], hv3 = hl4[3];
      for (int si = 0; si < 8; ++si) {
        int s = wid * 8 + si;
        const float4* ep = (const float4*)(encp + ((size_t)(b * 64 + s)) * NH + lane * 16);
        float4 e0 = ep[0], e1 = ep[1], e2 = ep[2], e3 = ep[3];
        float a = e0.x * hv0.x + e0.y * hv0.y + e0.z * hv0.z + e0.w * hv0.w;
        a = fmaf(e1.x, hv1.x, a); a = fmaf(e1.y, hv1.y, a);
        a = fmaf(e1.z, hv1.z, a); a = fmaf(e1.w, hv1.w, a);
        a = fmaf(e2.x, hv2.x, a); a = fmaf(e2.y, hv2.y, a);
        a = fmaf(e2.z, hv2.z, a); a = fmaf(e2.w, hv2.w, a);
        a = fmaf(e3.x, hv3.x, a); a = fmaf(e3.y, hv3.y, a);
        a = fmaf(e3.z, hv3.z, a); a = fmaf(e3.w, hv3.w, a);
#pragma unroll
        for (int off = 32; off; off >>= 1) a += __shfl_xor(a, off);
        if (lane == 0) sc_lds[s] = a;
      }
    }
    __syncthreads();
    if (tid < 64) {
      float sc = sc_lds[tid];
      float m = sc;
#pragma unroll
      for (int off = 32; off; off >>= 1) m = fmaxf(m, __shfl_xor(m, off));
      float e = expf(sc - m);
      float sum = e;
#pragma unroll
      for (int off = 32; off; off >>= 1) sum += __shfl_xor(sum, off);
      p_lds[tid] = e / sum;
    }
    __syncthreads();
    if (tid < 256) {
      int k4 = tid * 4;
      float a0 = 0, a1 = 0, a2 = 0, a3 = 0;
      const float* ep = encp + (size_t)(b * 64) * NH + k4;
      for (int s = 0; s < 64; ++s) {
        float p = p_lds[s];
        float4 e = *(const float4*)(ep + (size_t)s * NH);
        a0 = fmaf(p, e.x, a0); a1 = fmaf(p, e.y, a1);
        a2 = fmaf(p, e.z, a2); a3 = fmaf(p, e.w, a3);
      }
      short4v c4h, c4l;
      float av[4] = {a0, a1, a2, a3};
#pragma unroll
      for (int q = 0; q < 4; ++q) {
        short hh = f2bf(av[q]);
        c4h[q] = hh;
        c4l[q] = f2bf(av[q] - bf2f(hh));
      }
      *(short4v*)(ctxh + k4) = c4h;
      *(short4v*)(ctxl + k4) = c4l;
    }
  } else {
    // ---------------- Phase C: comb t = iter-2 (split-MFMA) ----------------
    const int t = iter - 2;
    if (t < 0) return;
    const int j0 = (blk - 160) * 16;
    const size_t hslot = (size_t)((t + 1) & 3) * (NH * NB);
    const size_t cslot = (size_t)(t & 1) * (NH * NB);
    // waves 0-3: h region (K 0..1024); waves 4-7: ctx region (K 1024..2048)
    const short* Ah = (wid < 4) ? (hhi_ring + hslot) : (ctxhi_ring + cslot);
    const short* Al = (wid < 4) ? (hlo_ring + hslot) : (ctxlo_ring + cslot);
    const int kb = (wid & 3) * 256;     // offset within region
    const int kabs = wid * 256;         // offset within full K=2048

    floatx4 acc[2] = {};
    const short* bhp = WcT_hi + (size_t)(j0 + rsel) * 2048 + kabs + kA;
    const short* blp = WcT_lo + (size_t)(j0 + rsel) * 2048 + kabs + kA;
    const short* a0hp = Ah + (size_t)rsel * NH + kb + kA;
    const short* a0lp = Al + (size_t)rsel * NH + kb + kA;
    const short* a1hp = Ah + (size_t)(16 + rsel) * NH + kb + kA;
    const short* a1lp = Al + (size_t)(16 + rsel) * NH + kb + kA;
#pragma unroll
    for (int kk = 0; kk < 8; ++kk) {
      int k0 = kk * 32;
      short8 a0h = *(const short8*)(a0hp + k0);
      short8 a0l = *(const short8*)(a0lp + k0);
      short8 a1h = *(const short8*)(a1hp + k0);
      short8 a1l = *(const short8*)(a1lp + k0);
      short8 b_h = *(const short8*)(bhp + k0);
      short8 b_l = *(const short8*)(blp + k0);
      acc[0] = __builtin_amdgcn_mfma_f32_16x16x32_bf16(a0l, b_h, acc[0], 0, 0, 0);
      acc[0] = __builtin_amdgcn_mfma_f32_16x16x32_bf16(a0h, b_l, acc[0], 0, 0, 0);
      acc[0] = __builtin_amdgcn_mfma_f32_16x16x32_bf16(a0h, b_h, acc[0], 0, 0, 0);
      acc[1] = __builtin_amdgcn_mfma_f32_16x16x32_bf16(a1l, b_h, acc[1], 0, 0, 0);
      acc[1] = __builtin_amdgcn_mfma_f32_16x16x32_bf16(a1h, b_l, acc[1], 0, 0, 0);
      acc[1] = __builtin_amdgcn_mfma_f32_16x16x32_bf16(a1h, b_h, acc[1], 0, 0, 0);
    }
    // partials -> LDS [wave][32 b][17-pad 16 cols]
#pragma unroll
    for (int mi = 0; mi < 2; ++mi)
#pragma unroll
      for (int i = 0; i < 4; ++i)
        smem[wid * 544 + (mi * 16 + crow + i) * 17 + ccol] = acc[mi][i];
    __syncthreads();
    {
      int b = tid & 31, jl = tid >> 5;   // jl 0..15
      float s = 0;
#pragma unroll
      for (int w = 0; w < 8; ++w) s += smem[w * 544 + b * 17 + jl];
      float v = tanhf(s + bcomb[j0 + jl]);
      outs[((size_t)b * TDEC + t) * NH + j0 + jl] = f2bf(v);
    }
  }
}

// ---------------------------------------------------------------------------
extern "C" void kernel_launch(void* const* d_in, const int* in_sizes, int n_in,
                              void* d_out, int out_size, void* d_ws, size_t ws_size,
                              hipStream_t stream)
{
  const int*   target = (const int*)  d_in[0];
  const float* src    = (const float*)d_in[1];
  const float* h0     = (const float*)d_in[2];
  const float* c0     = (const float*)d_in[3];
  const float* emb    = (const float*)d_in[4];
  const float* Wih    = (const float*)d_in[5];
  const float* Whh    = (const float*)d_in[6];
  const float* brnn   = (const float*)d_in[7];
  const float* Wattn  = (const float*)d_in[8];
  const float* battn  = (const float*)d_in[9];
  const float* Wcomb  = (const float*)d_in[10];
  const float* bcomb  = (const float*)d_in[11];
  const float* Wout   = (const float*)d_in[12];
  const float* bout   = (const float*)d_in[13];
  float* out = (float*)d_out;

  char* ws = (char*)d_ws;
  size_t off = 0;
  auto take = [&](size_t bytes) { char* p = ws + off; off += (bytes + 255) & ~(size_t)255; return p; };
  short* WoutT    = (short*)take((size_t)NV * NH * 2);          // 64 MB
  short* WattnTh  = (short*)take((size_t)NH * 2048 * 2);        // 4 MB
  short* WattnTl  = (short*)take((size_t)NH * 2048 * 2);        // 4 MB
  short* WihTp    = (short*)take((size_t)4096 * NE * 2);        // 4 MB (perm rows)
  short* WhpHi    = (short*)take((size_t)4096 * NH * 2);        // 8 MB (perm rows)
  short* WhpLo    = (short*)take((size_t)4096 * NH * 2);        // 8 MB
  short* WcTHi    = (short*)take((size_t)NH * 2048 * 2);        // 4 MB
  short* WcTLo    = (short*)take((size_t)NH * 2048 * 2);        // 4 MB
  short* xs_bf    = (short*)take((size_t)TDEC * NB * NE * 2);   // 2 MB
  float* encp     = (float*)take((size_t)NB * NS * NH * 4);     // 8 MB (fp32)
  short* gatesx   = (short*)take((size_t)TDEC * NB * 4096 * 2); // 16.5 MB (perm cols)
  short* outs_bf  = (short*)take((size_t)TDEC * NB * NH * 2);   // 4 MB
  short* hhi_ring = (short*)take((size_t)4 * NH * NB * 2);
  short* hlo_ring = (short*)take((size_t)4 * NH * NB * 2);
  float* hf_ring  = (float*)take((size_t)4 * NH * NB * 4);
  short* ctxhi_rg = (short*)take((size_t)2 * NH * NB * 2);
  short* ctxlo_rg = (short*)take((size_t)2 * NH * NB * 2);
  float* c_buf    = (float*)take((size_t)NH * NB * 4);
  float* brnn_p   = (float*)take((size_t)4096 * 4);
  if (off > ws_size) return;

  // 1) weight transposes
  transpose_bf_split<0><<<dim3(2048 / 32, NH / 32), 256, 0, stream>>>(Wattn, WattnTh, WattnTl, 2048, NH);
  transpose_bf<1><<<dim3(NE / 32, 4096 / 32), 256, 0, stream>>>(Wih, WihTp, NE, 4096);
  transpose_bf_split<1><<<dim3(NH / 32, 4096 / 32), 256, 0, stream>>>(Whh, WhpHi, WhpLo, NH, 4096);
  transpose_bf_split<0><<<dim3(2048 / 32, NH / 32), 256, 0, stream>>>(Wcomb, WcTHi, WcTLo, 2048, NH);
  transpose_bf<0><<<dim3(NH / 32, NV / 32), 256, 0, stream>>>(Wout, WoutT, NH, NV);
  // 2) gathers / inits
  gather_init<<<1024, 256, 0, stream>>>(target, emb, h0, c0, brnn,
                                        xs_bf, hf_ring, hhi_ring, hlo_ring, c_buf, brnn_p);
  // 3) enc_proj = src_enc @ W_attn + b_attn  (fp32-accurate split GEMM)
  gemm_split<<<dim3(16, NH / 128), 256, 0, stream>>>(src, WattnTh, WattnTl, encp, battn, 2048, NH, 2048);
  // 4) gates_x = xs @ W_ih + b_rnn  (permuted columns c = 4j+gate)
  gemm_kernel<1><<<dim3(16, 4096 / 128), 256, 0, stream>>>(xs_bf, WihTp, gatesx, brnn_p, TDEC * NB, 4096, NE);
  // 5) pipelined scan: 65 iterations, 224 blocks x 512 threads
  for (int i = 0; i < TDEC + 2; ++i)
    scan_step<<<224, 512, 0, stream>>>(i, WhpHi, WhpLo, WcTHi, WcTLo, bcomb, encp, gatesx,
                                       hhi_ring, hlo_ring, hf_ring, ctxhi_rg, ctxlo_rg,
                                       c_buf, outs_bf);
  // 6) logits = outs @ W_out + b_out
  gemm_kernel<0><<<dim3(16, NV / 128), 256, 0, stream>>>(outs_bf, WoutT, out, bout, TDEC * NB, NV, NH);
}